// Round 6
// baseline (10126.952 us; speedup 1.0000x reference)
//
#include <hip/hip_runtime.h>
#include <hip/hip_bf16.h>

// DGL child-sum TreeLSTM, level-synchronous leaves->root, gather-based.
// Round 6: clean baseline. Established facts:
//  - float inputs fp32, x/par int32 (probe + NaN differential, r2/r3)
//  - OUTPUT fp32 (r5: fp32 marker 72.0 read back exactly)
//  - tree pipeline internally healthy (r5 invariants: build count, fan-in,
//    c range, h_root range all passed; the one failing bit was a false
//    positive - cA holds a mix of odd levels, not just leaves)
// Main path: probe -> build child lists -> 12 fused level kernels (bf16
// ping-pong state) -> fp32 final linear. Diagnostics removed.

#define B_G     32
#define NPG     4095
#define NTOT    (B_G * NPG)
#define NCLS    104
#define VOCAB   20000
#define PAD_TOK 19999
#define KCAP    24

typedef unsigned short u16;
typedef unsigned int   u32;

__device__ __forceinline__ float bf2f(u16 v) {
    union { u32 u; float f; } x; x.u = ((u32)v) << 16; return x.f;
}
__device__ __forceinline__ u16 f2bf(float f) {
    union { __hip_bfloat16 h; u16 u; } c; c.h = __float2bfloat16(f); return c.u;
}
__device__ __forceinline__ void load8(const void* base, int idx, int isf32, float* w) {
    if (isf32) {
        const float* f = (const float*)base + idx;
        float4 a = *(const float4*)f;
        float4 b = *(const float4*)(f + 4);
        w[0]=a.x; w[1]=a.y; w[2]=a.z; w[3]=a.w;
        w[4]=b.x; w[5]=b.y; w[6]=b.z; w[7]=b.w;
    } else {
        uint4 u = *(const uint4*)((const u16*)base + idx);
        union { u32 q; float f; } t;
        t.q = u.x << 16;          w[0] = t.f;
        t.q = u.x & 0xffff0000u;  w[1] = t.f;
        t.q = u.y << 16;          w[2] = t.f;
        t.q = u.y & 0xffff0000u;  w[3] = t.f;
        t.q = u.z << 16;          w[4] = t.f;
        t.q = u.z & 0xffff0000u;  w[5] = t.f;
        t.q = u.w << 16;          w[6] = t.f;
        t.q = u.w & 0xffff0000u;  w[7] = t.f;
    }
}
__device__ __forceinline__ float loadv(const void* b, int i, int isf32) {
    return isf32 ? ((const float*)b)[i] : bf2f(((const u16*)b)[i]);
}
__device__ __forceinline__ float sigf(float x) { return 1.f / (1.f + __expf(-x)); }

// --------------------------- dtype probe -----------------------------------
__global__ void probe_kernel(const void* emb, const void* Wiou, const void* Uiou,
                             const void* Ufw, const void* lw,
                             const int* x32, const int* par32, int* flags)
{
    if (threadIdx.x != 0 || blockIdx.x != 0) return;
    const void* ptrs[5] = { emb, Wiou, Uiou, Ufw, lw };
    for (int i = 0; i < 5; ++i) {
        const u16* p = (const u16*)ptrs[i];
        int big = 0;
        for (int k = 0; k < 128; ++k) {
            u32 e = (((u32)p[k]) << 16 >> 23) & 0xFF;
            if (e >= 129) ++big;
        }
        flags[i] = (big >= 4) ? 1 : 0;
    }
    int zx = 1;
    for (int k = 1; k <= 15; k += 2) if (x32[k] != 0) zx = 0;
    flags[5] = zx;
    flags[6] = (par32[3] == 0 && par32[5] == 0) ? 1 : 0;
}

// --------------------------- child-list build ------------------------------
__global__ __launch_bounds__(256) void build_kernel(
    const int* __restrict__ par, int* __restrict__ cnt, int* __restrict__ bucket,
    const int* __restrict__ flags)
{
    int gid = blockIdx.x * 256 + threadIdx.x;
    if (gid >= NTOT) return;
    int g     = (int)((u32)gid / NPG);
    int local = gid - g * NPG;
    if (local == 0) return;
    int v  = local + 1;
    int cl = 31 - __clz(v);
    int j  = local - ((1 << cl) - 1);
    int p  = flags[6] ? par[2 * gid] : par[gid];
    p = max(0, min(p, NTOT - 1));
    int pg = (int)((u32)p / NPG);
    int pl = p - pg * NPG;
    int d  = cl - 1;
    int pbase = B_G * ((1 << d) - 1);
    int ps = pbase + (pg << d) + (pl - ((1 << d) - 1));
    ps = max(0, min(ps, 65503));
    int slot = atomicAdd(&cnt[ps], 1);
    if (slot < KCAP) bucket[(size_t)ps * KCAP + slot] = (g << cl) + j;
}

// --------------------------- fused level kernel ----------------------------
__global__ __launch_bounds__(256) void level_kernel(
    int d, int has_children,
    const int* __restrict__ x, const void* __restrict__ emb,
    const void* __restrict__ Wiou, const void* __restrict__ Uiou,
    const void* __restrict__ biou,
    const void* __restrict__ Ufw, const void* __restrict__ Ufb,
    const u16* __restrict__ hch, const u16* __restrict__ cch,
    u16* __restrict__ hout, u16* __restrict__ cout,
    const int* __restrict__ cnt, const int* __restrict__ bucket,
    const int* __restrict__ flags)
{
    __shared__ float xs[4][256];
    __shared__ float hts[4][256];
    __shared__ float cas[4][256];
    __shared__ float chh[256];
    __shared__ int toks[4];
    __shared__ int cnts[4];
    const int t  = threadIdx.x;
    const int pb = blockIdx.x * 4;
    const int f_emb = flags[0], f_wio = flags[1], f_uio = flags[2], f_uf = flags[3];

    if (t < 4) {
        int n     = pb + t;
        int graph = n >> d;
        int j     = n & ((1 << d) - 1);
        int gid   = graph * NPG + ((1 << d) - 1) + j;
        int tok   = flags[5] ? x[2 * gid] : x[gid];
        if (tok < 0 || tok >= VOCAB) tok = PAD_TOK;
        toks[t]   = tok;
        cnts[t]   = has_children ? min(cnt[B_G * ((1 << d) - 1) + n], KCAP) : 0;
    }
    __syncthreads();

    #pragma unroll
    for (int i = 0; i < 4; ++i) {
        int tok  = toks[i];
        xs[i][t] = (tok == PAD_TOK) ? 0.f : loadv(emb, tok * 256 + t, f_emb);
        hts[i][t] = 0.f;
        cas[i][t] = 0.f;
    }

    if (has_children) {
        const int pbase = B_G * ((1 << d) - 1);
        const int nlim  = (B_G << (d + 1)) - 1;
        for (int i = 0; i < 4; ++i) {
            int nc = cnts[i];
            for (int ci = 0; ci < nc; ++ci) {
                int child = bucket[(size_t)(pbase + pb + i) * KCAP + ci];
                child = max(0, min(child, nlim));
                float hv = bf2f(hch[(size_t)child * 256 + t]);
                float cv = bf2f(cch[(size_t)child * 256 + t]);
                __syncthreads();
                chh[t] = hv;
                __syncthreads();
                float acc = 0.f;
                for (int k0 = 0; k0 < 256; k0 += 8) {
                    float wf[8]; load8(Ufw, t * 256 + k0, f_uf, wf);
                    #pragma unroll
                    for (int jj = 0; jj < 8; ++jj) acc += wf[jj] * chh[k0 + jj];
                }
                float f = sigf(acc + loadv(Ufb, t, f_uf));
                cas[i][t] += f * cv;
                hts[i][t] += hv;
            }
        }
    }
    __syncthreads();

    float a0[4] = {0,0,0,0}, a1[4] = {0,0,0,0}, a2[4] = {0,0,0,0};
    for (int k0 = 0; k0 < 256; k0 += 8) {
        float f0[8], f1[8], f2[8];
        load8(Wiou, t * 256 + k0,           f_wio, f0);
        load8(Wiou, (t + 256) * 256 + k0,   f_wio, f1);
        load8(Wiou, (t + 512) * 256 + k0,   f_wio, f2);
        #pragma unroll
        for (int i = 0; i < 4; ++i) {
            const float* xr = &xs[i][k0];
            #pragma unroll
            for (int jj = 0; jj < 8; ++jj) {
                float xv = xr[jj];
                a0[i] += f0[jj] * xv; a1[i] += f1[jj] * xv; a2[i] += f2[jj] * xv;
            }
        }
    }
    if (has_children) {
        for (int k0 = 0; k0 < 256; k0 += 8) {
            float f0[8], f1[8], f2[8];
            load8(Uiou, t * 256 + k0,           f_uio, f0);
            load8(Uiou, (t + 256) * 256 + k0,   f_uio, f1);
            load8(Uiou, (t + 512) * 256 + k0,   f_uio, f2);
            #pragma unroll
            for (int i = 0; i < 4; ++i) {
                const float* hr = &hts[i][k0];
                #pragma unroll
                for (int jj = 0; jj < 8; ++jj) {
                    float hv = hr[jj];
                    a0[i] += f0[jj] * hv; a1[i] += f1[jj] * hv; a2[i] += f2[jj] * hv;
                }
            }
        }
    }

    float b0 = loadv(biou, t,       f_wio);
    float b1 = loadv(biou, t + 256, f_wio);
    float b2 = loadv(biou, t + 512, f_wio);
    #pragma unroll
    for (int i = 0; i < 4; ++i) {
        float cnew = sigf(a0[i] + b0) * tanhf(a2[i] + b2) + cas[i][t];
        float hnew = sigf(a1[i] + b1) * tanhf(cnew);
        size_t off = (size_t)(pb + i) * 256 + t;
        hout[off] = f2bf(hnew);
        cout[off] = f2bf(cnew);
    }
}

// --------------------------- final linear (fp32 out) -----------------------
__global__ __launch_bounds__(128) void final_kernel(
    const u16* __restrict__ hroot,
    const void* __restrict__ lw, const void* __restrict__ lb,
    float* __restrict__ out, const int* __restrict__ flags)
{
    __shared__ float hr[256];
    const int g = blockIdx.x;
    const int t = threadIdx.x;
    const int f_lw = flags[4];
    hr[t]       = bf2f(hroot[(size_t)g * 256 + t]);
    hr[t + 128] = bf2f(hroot[(size_t)g * 256 + t + 128]);
    __syncthreads();
    if (t < NCLS) {
        float acc = 0.f;
        for (int k0 = 0; k0 < 256; k0 += 8) {
            float wf[8]; load8(lw, t * 256 + k0, f_lw, wf);
            #pragma unroll
            for (int jj = 0; jj < 8; ++jj) acc += wf[jj] * hr[k0 + jj];
        }
        acc += loadv(lb, t, f_lw);
        out[(size_t)g * NCLS + t] = acc;
    }
}

__global__ void fill_kernel(float* out, int n, float v) {
    int i = blockIdx.x * 256 + threadIdx.x;
    if (i < n) out[i] = v;
}

extern "C" void kernel_launch(void* const* d_in, const int* in_sizes, int n_in,
                              void* d_out, int out_size, void* d_ws, size_t ws_size,
                              hipStream_t stream)
{
    float* out = (float*)d_out;

    static const int exp_sizes[10] = {131040, 131040, 5120000, 196608, 196608,
                                      768, 65536, 256, 26624, 104};
    bool shapes_ok = (n_in == 10) && (out_size == B_G * NCLS);
    for (int i = 0; i < 10 && shapes_ok; ++i)
        if (in_sizes[i] != exp_sizes[i]) shapes_ok = false;
    if (!shapes_ok) {
        fill_kernel<<<(out_size + 255) / 256, 256, 0, stream>>>(out, out_size, 2.0f);
        return;
    }

    const int* x     = (const int*)d_in[0];
    const int* par   = (const int*)d_in[1];
    const void* emb  = d_in[2];
    const void* Wiou = d_in[3];
    const void* Uiou = d_in[4];
    const void* biou = d_in[5];
    const void* Ufw  = d_in[6];
    const void* Ufb  = d_in[7];
    const void* lw   = d_in[8];
    const void* lb   = d_in[9];

    const size_t NA = (size_t)65536 * 256;   // odd levels (11,9,...,1)
    const size_t NB = (size_t)32768 * 256;   // even levels (10,8,...,0)
    u16* hA = (u16*)d_ws;
    u16* hB = hA + NA;
    u16* cA = hB + NB;
    u16* cB = cA + NA;
    int* cnt    = (int*)(cB + NB);           // 65536 ints; [0,65504) counters
    int* bucket = cnt + 65536;
    int* flags  = cnt + 65504;               // 7 ints (tail of cnt region)
    const size_t needed = (2 * (NA + NB)) * sizeof(u16)
                        + 65536 * sizeof(int) + (size_t)65536 * KCAP * sizeof(int);
    if (ws_size < needed) {                  // 107,216,896 B (r3-r5 show it fits)
        fill_kernel<<<(out_size + 255) / 256, 256, 0, stream>>>(out, out_size, 1.0f);
        return;
    }

    hipMemsetAsync(cnt, 0, 65536 * sizeof(int), stream);
    probe_kernel<<<1, 1, 0, stream>>>(emb, Wiou, Uiou, Ufw, lw, x, par, flags);
    build_kernel<<<(NTOT + 255) / 256, 256, 0, stream>>>(par, cnt, bucket, flags);

    for (int d = 11; d >= 0; --d) {
        const int NN = B_G << d;
        u16* hout = (d & 1) ? hA : hB;
        u16* cout = (d & 1) ? cA : cB;
        const u16* hch = ((d + 1) & 1) ? hA : hB;
        const u16* cch = ((d + 1) & 1) ? cA : cB;
        level_kernel<<<NN / 4, 256, 0, stream>>>(
            d, (d < 11) ? 1 : 0, x, emb, Wiou, Uiou, biou, Ufw, Ufb,
            hch, cch, hout, cout, cnt, bucket, flags);
    }
    final_kernel<<<B_G, 128, 0, stream>>>(hB, lw, lb, out, flags);
}

// Round 7
// 1179.985 us; speedup vs baseline: 8.5823x; 8.5823x over previous
//
#include <hip/hip_runtime.h>
#include <hip/hip_bf16.h>

// DGL child-sum TreeLSTM. Round 7: MFMA GEMM fast path + r6 VALU fallback.
// Facts: float inputs fp32, x/par int32 (probed), output fp32, r6 passed
// at 10.1ms with MfmaUtil=0 / VALUBusy=21% (latency-bound VALU matvec).
// Fast path per level: GEMM1 (f-gate, epilogue: fp32 atomics f*c->Cagg,
// h->Htild) ; GEMM2 ([X|Htild]@[Wiou|Uiou]^T, K=512, gates fused in
// epilogue). Weights pre-converted to K-chunked bf16. ws need 153.0 MB;
// if smaller, run the r6 baseline path (known-pass at 107.2 MB).

#define B_G     32
#define NPG     4095
#define NTOT    (B_G * NPG)
#define NCLS    104
#define VOCAB   20000
#define PAD_TOK 19999
#define KCAP    24
#define LB(d)   (32 * ((1 << (d)) - 1))   // level base offset in level-major order

typedef unsigned short u16;
typedef unsigned int   u32;
typedef __attribute__((ext_vector_type(8))) short bfrag8;  // 8 bf16 (4 VGPR)
typedef __attribute__((ext_vector_type(4))) float ffrag4;  // 4 f32 acc

__device__ __forceinline__ float bf2f(u16 v) {
    union { u32 u; float f; } x; x.u = ((u32)v) << 16; return x.f;
}
__device__ __forceinline__ u16 f2bf(float f) {
    union { __hip_bfloat16 h; u16 u; } c; c.h = __float2bfloat16(f); return c.u;
}
__device__ __forceinline__ void load8(const void* base, int idx, int isf32, float* w) {
    if (isf32) {
        const float* f = (const float*)base + idx;
        float4 a = *(const float4*)f;
        float4 b = *(const float4*)(f + 4);
        w[0]=a.x; w[1]=a.y; w[2]=a.z; w[3]=a.w;
        w[4]=b.x; w[5]=b.y; w[6]=b.z; w[7]=b.w;
    } else {
        uint4 u = *(const uint4*)((const u16*)base + idx);
        union { u32 q; float f; } t;
        t.q = u.x << 16;          w[0] = t.f;
        t.q = u.x & 0xffff0000u;  w[1] = t.f;
        t.q = u.y << 16;          w[2] = t.f;
        t.q = u.y & 0xffff0000u;  w[3] = t.f;
        t.q = u.z << 16;          w[4] = t.f;
        t.q = u.z & 0xffff0000u;  w[5] = t.f;
        t.q = u.w << 16;          w[6] = t.f;
        t.q = u.w & 0xffff0000u;  w[7] = t.f;
    }
}
__device__ __forceinline__ float loadv(const void* b, int i, int isf32) {
    return isf32 ? ((const float*)b)[i] : bf2f(((const u16*)b)[i]);
}
__device__ __forceinline__ float sigf(float x) { return 1.f / (1.f + __expf(-x)); }

// --------------------------- dtype probe (shared) ---------------------------
__global__ void probe_kernel(const void* emb, const void* Wiou, const void* Uiou,
                             const void* Ufw, const void* lw,
                             const int* x32, const int* par32, int* flags)
{
    if (threadIdx.x != 0 || blockIdx.x != 0) return;
    const void* ptrs[5] = { emb, Wiou, Uiou, Ufw, lw };
    for (int i = 0; i < 5; ++i) {
        const u16* p = (const u16*)ptrs[i];
        int big = 0;
        for (int k = 0; k < 128; ++k) {
            u32 e = (((u32)p[k]) << 16 >> 23) & 0xFF;
            if (e >= 129) ++big;
        }
        flags[i] = (big >= 4) ? 1 : 0;     // 1 => fp32
    }
    int zx = 1;
    for (int k = 1; k <= 15; k += 2) if (x32[k] != 0) zx = 0;
    flags[5] = zx;                         // 1 => x int64
    flags[6] = (par32[3] == 0 && par32[5] == 0) ? 1 : 0;  // 1 => par int64
}

// =========================== FAST PATH (MFMA) ===============================

// tokLvl[lp] = token per level-major position; parLvl[lp] = parent LEVEL-LOCAL idx
__global__ __launch_bounds__(256) void tokpar_kernel(
    const int* __restrict__ x, const int* __restrict__ par,
    int* __restrict__ tokLvl, int* __restrict__ parLvl,
    const int* __restrict__ flags)
{
    int gid = blockIdx.x * 256 + threadIdx.x;
    if (gid >= NTOT) return;
    int g     = (int)((u32)gid / NPG);
    int local = gid - g * NPG;
    int v  = local + 1;
    int d  = 31 - __clz(v);
    int j  = local - ((1 << d) - 1);
    int lp = LB(d) + (g << d) + j;
    int tok = flags[5] ? x[2 * gid] : x[gid];
    if (tok < 0 || tok >= VOCAB) tok = PAD_TOK;
    tokLvl[lp] = tok;
    if (local > 0) {
        int p  = flags[6] ? par[2 * gid] : par[gid];
        p = max(0, min(p, NTOT - 1));
        int pg = (int)((u32)p / NPG);
        int pl = p - pg * NPG;
        int pd = d - 1;
        int np = (pg << pd) + (pl - ((1 << pd) - 1));
        np = max(0, min(np, (B_G << pd) - 1));
        parLvl[lp] = np;
    }
}

// combined [Wiou|Uiou] -> bf16, K-chunked layout wuc[c][768][32], c=0..15
__global__ __launch_bounds__(256) void wuc_kernel(
    const void* __restrict__ Wiou, const void* __restrict__ Uiou,
    u16* __restrict__ wuc, const int* __restrict__ flags)
{
    int idx = blockIdx.x * 256 + threadIdx.x;
    if (idx >= 16 * 768 * 32) return;
    int c   = idx / 24576;
    int rem = idx - c * 24576;
    int out = rem >> 5;
    int kk  = rem & 31;
    int k   = c * 32 + kk;
    float v = (k < 256) ? loadv(Wiou, out * 256 + k, flags[1])
                        : loadv(Uiou, out * 256 + (k - 256), flags[2]);
    wuc[idx] = f2bf(v);
}

// Ufw -> bf16, chunked ufc[c][256][32], c=0..7
__global__ __launch_bounds__(256) void ufc_kernel(
    const void* __restrict__ Ufw, u16* __restrict__ ufc,
    const int* __restrict__ flags)
{
    int idx = blockIdx.x * 256 + threadIdx.x;
    if (idx >= 8 * 256 * 32) return;
    int c   = idx >> 13;
    int rem = idx & 8191;
    int out = rem >> 5;
    int kk  = rem & 31;
    ufc[idx] = f2bf(loadv(Ufw, out * 256 + c * 32 + kk, flags[3]));
}

// GEMM1: Fraw = H_ch @ Ufw^T ; epilogue f=sig(raw+b), atomics:
//   cagg[parent][t] += f * c_ch ; htild[parent][t] += h_ch
// M-tile 32 children/block, N=256, K=256 (8 chunks of 32).
__global__ __launch_bounds__(256) void gemm1_kernel(
    const u16* __restrict__ hch, const void* cch, int cch_f32,
    const u16* __restrict__ ufc, const void* __restrict__ ufb,
    const int* __restrict__ parLvl_cl,
    float* cagg, float* htild, const int* __restrict__ flags)
{
    __shared__ u16 As[32][40];
    __shared__ u16 Bs[256][40];
    __shared__ int pl[32];
    const int t = threadIdx.x;
    const int w = t >> 6, lane = t & 63, quad = lane >> 4, l15 = lane & 15;
    const int m0 = blockIdx.x * 32;
    const int f_uf = flags[3];
    if (t < 32) pl[t] = parLvl_cl[m0 + t];
    __syncthreads();

    ffrag4 acc[2][4];
    #pragma unroll
    for (int i = 0; i < 2; ++i)
        #pragma unroll
        for (int j = 0; j < 4; ++j) acc[i][j] = (ffrag4)0.f;

    const int arow = t >> 3, aseg = t & 7;
    const int brow0 = t >> 2, bseg = t & 3;
    for (int c = 0; c < 8; ++c) {
        *(uint2*)&As[arow][aseg * 4] =
            *(const uint2*)(hch + (size_t)(m0 + arow) * 256 + c * 32 + aseg * 4);
        #pragma unroll
        for (int r16 = 0; r16 < 4; ++r16) {
            int row = r16 * 64 + brow0;
            *(uint4*)&Bs[row][bseg * 8] =
                *(const uint4*)(ufc + ((size_t)c * 256 + row) * 32 + bseg * 8);
        }
        __syncthreads();
        bfrag8 a[2], b[4];
        #pragma unroll
        for (int mt = 0; mt < 2; ++mt) a[mt] = *(bfrag8*)&As[mt * 16 + l15][quad * 8];
        #pragma unroll
        for (int nt = 0; nt < 4; ++nt) b[nt] = *(bfrag8*)&Bs[w * 64 + nt * 16 + l15][quad * 8];
        #pragma unroll
        for (int mt = 0; mt < 2; ++mt)
            #pragma unroll
            for (int nt = 0; nt < 4; ++nt)
                acc[mt][nt] = __builtin_amdgcn_mfma_f32_16x16x32_bf16(a[mt], b[nt], acc[mt][nt], 0, 0, 0);
        __syncthreads();
    }

    #pragma unroll
    for (int nt = 0; nt < 4; ++nt) {
        int hu = w * 64 + nt * 16 + l15;
        float fb = loadv(ufb, hu, f_uf);
        #pragma unroll
        for (int mt = 0; mt < 2; ++mt) {
            #pragma unroll
            for (int r = 0; r < 4; ++r) {
                int nl   = mt * 16 + quad * 4 + r;      // node local to block
                int node = m0 + nl;
                float f  = sigf(acc[mt][nt][r] + fb);
                float cv = cch_f32 ? ((const float*)cch)[(size_t)node * 256 + hu]
                                   : bf2f(((const u16*)cch)[(size_t)node * 256 + hu]);
                float hv = bf2f(hch[(size_t)node * 256 + hu]);
                int p = pl[nl];
                unsafeAtomicAdd(&cagg[(size_t)p * 256 + hu], f * cv);
                unsafeAtomicAdd(&htild[(size_t)p * 256 + hu], hv);
            }
        }
    }
}

// GEMM2: IOU = [X | Htild] @ [Wiou|Uiou]^T, gates fused in epilogue.
// M-tile 32 nodes/block, N=768 (wave w owns hidden units 64w..64w+63 for
// all three gates via interleaved N-tiles), K = 32*nchunk (8 leaf / 16).
__global__ __launch_bounds__(256) void gemm2_kernel(
    int nchunk,
    const int* __restrict__ tokLvl_d, const void* __restrict__ emb,
    const u16* __restrict__ wuc, const float* __restrict__ htild,
    const void* __restrict__ biou, const float* cagg,
    u16* __restrict__ hdst, void* cdst, int cdst_f32,
    const int* __restrict__ flags)
{
    __shared__ u16 As[32][40];
    __shared__ u16 Bs[768][40];
    __shared__ int toks[32];
    const int t = threadIdx.x;
    const int w = t >> 6, lane = t & 63, quad = lane >> 4, l15 = lane & 15;
    const int m0 = blockIdx.x * 32;
    const int f_emb = flags[0], f_b = flags[1];
    if (t < 32) toks[t] = tokLvl_d[m0 + t];
    __syncthreads();

    ffrag4 acc[2][12];
    #pragma unroll
    for (int i = 0; i < 2; ++i)
        #pragma unroll
        for (int j = 0; j < 12; ++j) acc[i][j] = (ffrag4)0.f;

    const int arow = t >> 3, aseg = t & 7;
    const int brow0 = t >> 2, bseg = t & 3;
    for (int c = 0; c < nchunk; ++c) {
        // stage A chunk (32 nodes x 32 K) as bf16
        u16 av[4];
        if (c < 8) {
            int tok = toks[arow];
            if (tok == PAD_TOK) { av[0] = av[1] = av[2] = av[3] = 0; }
            else if (f_emb) {
                float4 v = *(const float4*)((const float*)emb + (size_t)tok * 256 + c * 32 + aseg * 4);
                av[0] = f2bf(v.x); av[1] = f2bf(v.y); av[2] = f2bf(v.z); av[3] = f2bf(v.w);
            } else {
                *(uint2*)av = *(const uint2*)((const u16*)emb + (size_t)tok * 256 + c * 32 + aseg * 4);
            }
        } else {
            float4 v = *(const float4*)(htild + (size_t)(m0 + arow) * 256 + (c - 8) * 32 + aseg * 4);
            av[0] = f2bf(v.x); av[1] = f2bf(v.y); av[2] = f2bf(v.z); av[3] = f2bf(v.w);
        }
        *(uint2*)&As[arow][aseg * 4] = *(uint2*)av;
        // stage B chunk (768 outs x 32 K)
        #pragma unroll
        for (int r16 = 0; r16 < 12; ++r16) {
            int row = r16 * 64 + brow0;
            *(uint4*)&Bs[row][bseg * 8] =
                *(const uint4*)(wuc + ((size_t)c * 768 + row) * 32 + bseg * 8);
        }
        __syncthreads();
        bfrag8 a[2], b[12];
        #pragma unroll
        for (int mt = 0; mt < 2; ++mt) a[mt] = *(bfrag8*)&As[mt * 16 + l15][quad * 8];
        #pragma unroll
        for (int g = 0; g < 3; ++g)
            #pragma unroll
            for (int st = 0; st < 4; ++st)
                b[g * 4 + st] = *(bfrag8*)&Bs[g * 256 + w * 64 + st * 16 + l15][quad * 8];
        #pragma unroll
        for (int mt = 0; mt < 2; ++mt)
            #pragma unroll
            for (int nt = 0; nt < 12; ++nt)
                acc[mt][nt] = __builtin_amdgcn_mfma_f32_16x16x32_bf16(a[mt], b[nt], acc[mt][nt], 0, 0, 0);
        __syncthreads();
    }

    #pragma unroll
    for (int st = 0; st < 4; ++st) {
        int hu = w * 64 + st * 16 + l15;
        float bi = loadv(biou, hu,       f_b);
        float bo = loadv(biou, 256 + hu, f_b);
        float bu = loadv(biou, 512 + hu, f_b);
        #pragma unroll
        for (int mt = 0; mt < 2; ++mt) {
            #pragma unroll
            for (int r = 0; r < 4; ++r) {
                int node = m0 + mt * 16 + quad * 4 + r;
                float iv = acc[mt][st][r]     + bi;
                float ov = acc[mt][4 + st][r] + bo;
                float uv = acc[mt][8 + st][r] + bu;
                float cg = cagg ? cagg[(size_t)node * 256 + hu] : 0.f;
                float cn = sigf(iv) * tanhf(uv) + cg;
                float hn = sigf(ov) * tanhf(cn);
                hdst[(size_t)node * 256 + hu] = f2bf(hn);
                if (cdst_f32) ((float*)cdst)[(size_t)node * 256 + hu] = cn;
                else          ((u16*)cdst)[(size_t)node * 256 + hu]   = f2bf(cn);
            }
        }
    }
}

// ====================== BASELINE PATH (r6, known-pass) ======================

__global__ __launch_bounds__(256) void build_kernel(
    const int* __restrict__ par, int* __restrict__ cnt, int* __restrict__ bucket,
    const int* __restrict__ flags)
{
    int gid = blockIdx.x * 256 + threadIdx.x;
    if (gid >= NTOT) return;
    int g     = (int)((u32)gid / NPG);
    int local = gid - g * NPG;
    if (local == 0) return;
    int v  = local + 1;
    int cl = 31 - __clz(v);
    int j  = local - ((1 << cl) - 1);
    int p  = flags[6] ? par[2 * gid] : par[gid];
    p = max(0, min(p, NTOT - 1));
    int pg = (int)((u32)p / NPG);
    int pl = p - pg * NPG;
    int d  = cl - 1;
    int pbase = B_G * ((1 << d) - 1);
    int ps = pbase + (pg << d) + (pl - ((1 << d) - 1));
    ps = max(0, min(ps, 65503));
    int slot = atomicAdd(&cnt[ps], 1);
    if (slot < KCAP) bucket[(size_t)ps * KCAP + slot] = (g << cl) + j;
}

__global__ __launch_bounds__(256) void level_kernel(
    int d, int has_children,
    const int* __restrict__ x, const void* __restrict__ emb,
    const void* __restrict__ Wiou, const void* __restrict__ Uiou,
    const void* __restrict__ biou,
    const void* __restrict__ Ufw, const void* __restrict__ Ufb,
    const u16* __restrict__ hch, const u16* __restrict__ cch,
    u16* __restrict__ hout, u16* __restrict__ cout,
    const int* __restrict__ cnt, const int* __restrict__ bucket,
    const int* __restrict__ flags)
{
    __shared__ float xs[4][256];
    __shared__ float hts[4][256];
    __shared__ float cas[4][256];
    __shared__ float chh[256];
    __shared__ int toks[4];
    __shared__ int cnts[4];
    const int t  = threadIdx.x;
    const int pb = blockIdx.x * 4;
    const int f_emb = flags[0], f_wio = flags[1], f_uio = flags[2], f_uf = flags[3];

    if (t < 4) {
        int n     = pb + t;
        int graph = n >> d;
        int j     = n & ((1 << d) - 1);
        int gid   = graph * NPG + ((1 << d) - 1) + j;
        int tok   = flags[5] ? x[2 * gid] : x[gid];
        if (tok < 0 || tok >= VOCAB) tok = PAD_TOK;
        toks[t]   = tok;
        cnts[t]   = has_children ? min(cnt[B_G * ((1 << d) - 1) + n], KCAP) : 0;
    }
    __syncthreads();

    #pragma unroll
    for (int i = 0; i < 4; ++i) {
        int tok  = toks[i];
        xs[i][t] = (tok == PAD_TOK) ? 0.f : loadv(emb, tok * 256 + t, f_emb);
        hts[i][t] = 0.f;
        cas[i][t] = 0.f;
    }

    if (has_children) {
        const int pbase = B_G * ((1 << d) - 1);
        const int nlim  = (B_G << (d + 1)) - 1;
        for (int i = 0; i < 4; ++i) {
            int nc = cnts[i];
            for (int ci = 0; ci < nc; ++ci) {
                int child = bucket[(size_t)(pbase + pb + i) * KCAP + ci];
                child = max(0, min(child, nlim));
                float hv = bf2f(hch[(size_t)child * 256 + t]);
                float cv = bf2f(cch[(size_t)child * 256 + t]);
                __syncthreads();
                chh[t] = hv;
                __syncthreads();
                float acc = 0.f;
                for (int k0 = 0; k0 < 256; k0 += 8) {
                    float wf[8]; load8(Ufw, t * 256 + k0, f_uf, wf);
                    #pragma unroll
                    for (int jj = 0; jj < 8; ++jj) acc += wf[jj] * chh[k0 + jj];
                }
                float f = sigf(acc + loadv(Ufb, t, f_uf));
                cas[i][t] += f * cv;
                hts[i][t] += hv;
            }
        }
    }
    __syncthreads();

    float a0[4] = {0,0,0,0}, a1[4] = {0,0,0,0}, a2[4] = {0,0,0,0};
    for (int k0 = 0; k0 < 256; k0 += 8) {
        float f0[8], f1[8], f2[8];
        load8(Wiou, t * 256 + k0,         f_wio, f0);
        load8(Wiou, (t + 256) * 256 + k0, f_wio, f1);
        load8(Wiou, (t + 512) * 256 + k0, f_wio, f2);
        #pragma unroll
        for (int i = 0; i < 4; ++i) {
            const float* xr = &xs[i][k0];
            #pragma unroll
            for (int jj = 0; jj < 8; ++jj) {
                float xv = xr[jj];
                a0[i] += f0[jj] * xv; a1[i] += f1[jj] * xv; a2[i] += f2[jj] * xv;
            }
        }
    }
    if (has_children) {
        for (int k0 = 0; k0 < 256; k0 += 8) {
            float f0[8], f1[8], f2[8];
            load8(Uiou, t * 256 + k0,         f_uio, f0);
            load8(Uiou, (t + 256) * 256 + k0, f_uio, f1);
            load8(Uiou, (t + 512) * 256 + k0, f_uio, f2);
            #pragma unroll
            for (int i = 0; i < 4; ++i) {
                const float* hr = &hts[i][k0];
                #pragma unroll
                for (int jj = 0; jj < 8; ++jj) {
                    float hv = hr[jj];
                    a0[i] += f0[jj] * hv; a1[i] += f1[jj] * hv; a2[i] += f2[jj] * hv;
                }
            }
        }
    }

    float b0 = loadv(biou, t,       f_wio);
    float b1 = loadv(biou, t + 256, f_wio);
    float b2 = loadv(biou, t + 512, f_wio);
    #pragma unroll
    for (int i = 0; i < 4; ++i) {
        float cnew = sigf(a0[i] + b0) * tanhf(a2[i] + b2) + cas[i][t];
        float hnew = sigf(a1[i] + b1) * tanhf(cnew);
        size_t off = (size_t)(pb + i) * 256 + t;
        hout[off] = f2bf(hnew);
        cout[off] = f2bf(cnew);
    }
}

// --------------------------- final linear (fp32 out) -----------------------
__global__ __launch_bounds__(128) void final_kernel(
    const u16* __restrict__ hroot,
    const void* __restrict__ lw, const void* __restrict__ lb,
    float* __restrict__ out, const int* __restrict__ flags)
{
    __shared__ float hr[256];
    const int g = blockIdx.x;
    const int t = threadIdx.x;
    const int f_lw = flags[4];
    hr[t]       = bf2f(hroot[(size_t)g * 256 + t]);
    hr[t + 128] = bf2f(hroot[(size_t)g * 256 + t + 128]);
    __syncthreads();
    if (t < NCLS) {
        float acc = 0.f;
        for (int k0 = 0; k0 < 256; k0 += 8) {
            float wf[8]; load8(lw, t * 256 + k0, f_lw, wf);
            #pragma unroll
            for (int jj = 0; jj < 8; ++jj) acc += wf[jj] * hr[k0 + jj];
        }
        acc += loadv(lb, t, f_lw);
        out[(size_t)g * NCLS + t] = acc;
    }
}

__global__ void fill_kernel(float* out, int n, float v) {
    int i = blockIdx.x * 256 + threadIdx.x;
    if (i < n) out[i] = v;
}

// ============================ launcher =====================================
extern "C" void kernel_launch(void* const* d_in, const int* in_sizes, int n_in,
                              void* d_out, int out_size, void* d_ws, size_t ws_size,
                              hipStream_t stream)
{
    float* out = (float*)d_out;

    static const int exp_sizes[10] = {131040, 131040, 5120000, 196608, 196608,
                                      768, 65536, 256, 26624, 104};
    bool shapes_ok = (n_in == 10) && (out_size == B_G * NCLS);
    for (int i = 0; i < 10 && shapes_ok; ++i)
        if (in_sizes[i] != exp_sizes[i]) shapes_ok = false;
    if (!shapes_ok) {
        fill_kernel<<<(out_size + 255) / 256, 256, 0, stream>>>(out, out_size, 2.0f);
        return;
    }

    const int* x     = (const int*)d_in[0];
    const int* par   = (const int*)d_in[1];
    const void* emb  = d_in[2];
    const void* Wiou = d_in[3];
    const void* Uiou = d_in[4];
    const void* biou = d_in[5];
    const void* Ufw  = d_in[6];
    const void* Ufb  = d_in[7];
    const void* lw   = d_in[8];
    const void* lb   = d_in[9];

    // ---------------- fast-path workspace layout (byte offsets) ------------
    char* W = (char*)d_ws;
    u16*   hA     = (u16*)(W + 0);             // bf16 [65536][256]  33.55MB
    u16*   hB     = (u16*)(W + 33554432);      // bf16 [32768][256]  16.78MB
    u16*   cA     = (u16*)(W + 50331648);      // bf16 [65536][256]  33.55MB
    float* caOdd  = (float*)(W + 67108864);    //   fp32 Cagg region (cA tail)
    float* cBf    = (float*)(W + 83886080);    // fp32 [32768][256]  33.55MB
    float* Htild  = (float*)(W + 117440512);   // fp32 [32768][256]  33.55MB
    u16*   WUc    = (u16*)(W + 150994944);     // bf16 [16][768][32]
    u16*   Ufc    = (u16*)(W + 151781376);     // bf16 [8][256][32]
    int*   tokLvl = (int*)(W + 151912448);
    int*   parLvl = (int*)(W + 152436736);
    int*   flagsF = (int*)(W + 152961024);
    const size_t FAST_NEED = 152961088;

    if (ws_size >= FAST_NEED) {
        probe_kernel<<<1, 1, 0, stream>>>(emb, Wiou, Uiou, Ufw, lw, x, par, flagsF);
        tokpar_kernel<<<(NTOT + 255) / 256, 256, 0, stream>>>(x, par, tokLvl, parLvl, flagsF);
        wuc_kernel<<<1536, 256, 0, stream>>>(Wiou, Uiou, WUc, flagsF);
        ufc_kernel<<<256, 256, 0, stream>>>(Ufw, Ufc, flagsF);

        for (int d = 11; d >= 0; --d) {
            const int NN = B_G << d;
            u16*  hdst = (d & 1) ? hA : hB;
            void* cdst = (d & 1) ? (void*)cA : (void*)cBf;
            const int cdst_f32 = !(d & 1);
            float* caggp = nullptr;
            if (d < 11) {
                const int cl = d + 1, NC = B_G << cl;
                const u16*  hch = (cl & 1) ? hA : hB;
                const void* cch = (cl & 1) ? (const void*)cA : (const void*)cBf;
                const int cch_f32 = !(cl & 1);
                caggp = (d & 1) ? caOdd : cBf;
                hipMemsetAsync(Htild, 0, (size_t)NN * 1024, stream);
                hipMemsetAsync(caggp, 0, (size_t)NN * 1024, stream);
                gemm1_kernel<<<NC / 32, 256, 0, stream>>>(
                    hch, cch, cch_f32, Ufc, Ufb, parLvl + LB(cl), caggp, Htild, flagsF);
            }
            gemm2_kernel<<<NN / 32, 256, 0, stream>>>(
                (d < 11) ? 16 : 8, tokLvl + LB(d), emb, WUc, Htild, biou,
                caggp, hdst, cdst, cdst_f32, flagsF);
        }
        final_kernel<<<B_G, 128, 0, stream>>>(hB, lw, lb, out, flagsF);
        return;
    }

    // ---------------- baseline path (r6, known-pass @107.2MB) --------------
    const size_t NA = (size_t)65536 * 256;
    const size_t NB = (size_t)32768 * 256;
    u16* bhA = (u16*)d_ws;
    u16* bhB = bhA + NA;
    u16* bcA = bhB + NB;
    u16* bcB = bcA + NA;
    int* cnt    = (int*)(bcB + NB);
    int* bucket = cnt + 65536;
    int* flags  = cnt + 65504;
    const size_t BASE_NEED = (2 * (NA + NB)) * sizeof(u16)
                           + 65536 * sizeof(int) + (size_t)65536 * KCAP * sizeof(int);
    if (ws_size < BASE_NEED) {
        fill_kernel<<<(out_size + 255) / 256, 256, 0, stream>>>(out, out_size, 1.0f);
        return;
    }

    hipMemsetAsync(cnt, 0, 65536 * sizeof(int), stream);
    probe_kernel<<<1, 1, 0, stream>>>(emb, Wiou, Uiou, Ufw, lw, x, par, flags);
    build_kernel<<<(NTOT + 255) / 256, 256, 0, stream>>>(par, cnt, bucket, flags);

    for (int d = 11; d >= 0; --d) {
        const int NN = B_G << d;
        u16* hout = (d & 1) ? bhA : bhB;
        u16* cout = (d & 1) ? bcA : bcB;
        const u16* hch = ((d + 1) & 1) ? bhA : bhB;
        const u16* cch = ((d + 1) & 1) ? bcA : bcB;
        level_kernel<<<NN / 4, 256, 0, stream>>>(
            d, (d < 11) ? 1 : 0, x, emb, Wiou, Uiou, biou, Ufw, Ufb,
            hch, cch, hout, cout, cnt, bucket, flags);
    }
    final_kernel<<<B_G, 128, 0, stream>>>(bhB, lw, lb, out, flags);
}